// Round 4
// baseline (432.294 us; speedup 1.0000x reference)
//
#include <hip/hip_runtime.h>
#include <hip/hip_cooperative_groups.h>
namespace cg = cooperative_groups;

// Fastformer additive attention, MI355X (round 10):
//   - round-9 phase bodies VERBATIM (gload_lds + XOR swizzle dbuf pipeline,
//     fused qs/ks, exp2 fold, XCD swizzle), but QK/stage1/stage2/VU/OUT are
//     fused into ONE cooperative kernel with 4 grid.sync()s -- removes 4
//     inter-kernel graph gaps and keeps qkws L2-warm across phases.
//   - 512 blocks x 256 thr, LDS 67.6KB -> exactly 2 blocks/CU co-resident.
//   - conv stays a separate full-occupancy launch.
//   - runtime fallback to the 5-kernel path if cooperative launch errors.
// Pipeline: conv -> mega{QK(+qsks) |sync| s1 |sync| s2 |sync| VU |sync| OUT}

#define SCL2 0.1803368801f   /* 0.125 * log2(e) */
typedef unsigned short u16;
typedef __attribute__((ext_vector_type(8))) short short8;   // 8 bf16 = 4 VGPR
typedef __attribute__((ext_vector_type(4))) float f32x4;

#define MFMA16(a, b, c) __builtin_amdgcn_mfma_f32_16x16x32_bf16((a), (b), (c), 0, 0, 0)

__device__ __forceinline__ float bf2f(u16 u) {
    union { unsigned int i; float f; } v; v.i = ((unsigned int)u) << 16; return v.f;
}
__device__ __forceinline__ u16 f2bf(float f) {
    union { float f; unsigned int i; } v; v.f = f;
    unsigned int x = v.i;
    return (u16)((x + 0x7FFFu + ((x >> 16) & 1u)) >> 16);
}

// async global->LDS, 16B per lane; LDS dest = wave-uniform base + lane*16
__device__ __forceinline__ void gload16(const u16* g, u16* l) {
    __builtin_amdgcn_global_load_lds(
        (__attribute__((address_space(1))) void*)(void*)g,
        (__attribute__((address_space(3))) void*)l, 16, 0, 0);
}

// ---------------------------------------------------------------------------
// f32 -> bf16: w_qkv | w_out | wq | wk | x   (contiguous ws block)
// ---------------------------------------------------------------------------
__global__ __launch_bounds__(256) void conv_kernel(
    const float* __restrict__ w_qkv, const float* __restrict__ w_out,
    const float* __restrict__ wq, const float* __restrict__ wk,
    const float* __restrict__ x, u16* __restrict__ wsb)
{
    const int idx = (blockIdx.x * 256 + threadIdx.x) * 4;
    const float* src; int off;
    if      (idx < 786432)  { src = w_qkv; off = idx; }
    else if (idx < 1048576) { src = w_out; off = idx - 786432; }
    else if (idx < 1114112) { src = wq;    off = idx - 1048576; }
    else if (idx < 1179648) { src = wk;    off = idx - 1114112; }
    else                    { src = x;     off = idx - 1179648; }
    float4 v = *(const float4*)(src + off);
    ushort4 o; o.x = f2bf(v.x); o.y = f2bf(v.y); o.z = f2bf(v.z); o.w = f2bf(v.w);
    *(ushort4*)(wsb + idx) = o;
}

// ---------------------------------------------------------------------------
// GEMM phase body: tile 128M x (NCT*16)N, BK=64, K=512, 256 thr (4 waves).
// Double-buffered gload_lds staging (linear LDS dest, source chunk swizzled
// with (lane&7)^(lane>>3)); fragment reads XOR chunk idx with (row&7).
// K-loop: stage(next buf) -> sched_barrier -> compute(cur) -> syncthreads.
// Final compute reads buf0; C bounce (padded stride) overlays buf1.
// Grid is always 512 virtual blocks (64 row-panels x 8 col-panels).
// ---------------------------------------------------------------------------
#define MQK 0
#define MVU 1
#define MOUT 2

template <int MODE, int NCT>
__device__ __forceinline__ void gemm_body(
    u16* sm, int flat,
    const u16* __restrict__ Ab, int lda, int acol,
    const u16* __restrict__ Wb, const float* __restrict__ bias,
    const float* __restrict__ kg, const u16* __restrict__ qkws_ro,
    u16* __restrict__ qkws, float* __restrict__ outp,
    float* __restrict__ qsout, float* __restrict__ ksout)
{
    constexpr int BN = NCT * 16;            // tile N
    constexpr int CST = BN + 8;             // padded bounce stride (u16)
    constexpr int ASZ = 128 * 64;           // A elems per buffer
    constexpr int BSZ = BN * 64;            // B elems per buffer
    constexpr int HALF = ASZ + BSZ;         // one double-buffer half
    u16* const Cb = sm + HALF;              // C bounce overlays buf1 only

    const int t = threadIdx.x;
    const int w = t >> 6, lane = t & 63, s = lane & 15, quad = lane >> 4;
    const int sx = lane & 7;                // row&7 of every fragment row read

    // T1: bijective XCD swizzle over the 512 virtual blocks
    const int swz = (flat & 7) * 64 + (flat >> 3);
    const int by = swz & 7, bx = swz >> 3;
    const int bm = bx * 128, jn0 = by * BN;

    const int r8 = lane >> 3;                       // staged row within 8-row group
    const int c8x = ((lane & 7) ^ r8) << 3;         // swizzled source chunk (u16)

    f32x4 acc[2][NCT];
#pragma unroll
    for (int i = 0; i < 2; ++i)
#pragma unroll
        for (int j = 0; j < NCT; ++j) acc[i][j] = (f32x4){0.f, 0.f, 0.f, 0.f};

    // per-wave staging bases: A rows [w*32, w*32+32), B rows [w*NCT*4, ...)
    const u16* ga = Ab + (size_t)(bm + w * 32 + r8) * lda + acol + c8x;
    const u16* gb = Wb + (size_t)(jn0 + w * (NCT * 4) + r8) * 512 + c8x;

    auto stage = [&](int buf, int kt) {
        u16* la = sm + buf * HALF + (w * 32) * 64;
        u16* lb = sm + buf * HALF + ASZ + (w * (NCT * 4)) * 64;
#pragma unroll
        for (int j = 0; j < 4; ++j)
            gload16(ga + (size_t)j * 8 * lda + kt, la + j * 8 * 64);
#pragma unroll
        for (int j = 0; j < NCT / 2; ++j)
            gload16(gb + (size_t)j * 8 * 512 + kt, lb + j * 8 * 64);
    };
    auto compute = [&](int buf) {
        const u16* Ab_ = sm + buf * HALF;
        const u16* Bb_ = Ab_ + ASZ;
#pragma unroll
        for (int kk = 0; kk < 2; ++kk) {
            const int ca = ((kk * 4 + quad) ^ sx) << 3;   // swizzled read chunk
            short8 a0 = *(const short8*)&Ab_[(w * 32 + s) * 64 + ca];
            short8 a1 = *(const short8*)&Ab_[(w * 32 + 16 + s) * 64 + ca];
#pragma unroll
            for (int ct = 0; ct < NCT; ++ct) {
                short8 bf = *(const short8*)&Bb_[(ct * 16 + s) * 64 + ca];
                acc[0][ct] = MFMA16(a0, bf, acc[0][ct]);
                acc[1][ct] = MFMA16(a1, bf, acc[1][ct]);
            }
        }
    };

    // Pipeline: prologue stages tile0 into buf1; computes alternate 1,0,1,...
    stage(1, 0);
    __syncthreads();
#pragma unroll
    for (int it = 0; it < 7; ++it) {
        const int cur = 1 - (it & 1);
        stage(1 - cur, 64 * (it + 1));            // issue next-tile loads
        __builtin_amdgcn_sched_barrier(0);        // pin issue-before-compute
        compute(cur);
        __syncthreads();                          // drains prefetch; guards WAR
    }
    compute(0);

    if constexpr (MODE == MOUT) {
#pragma unroll
        for (int mt = 0; mt < 2; ++mt)
#pragma unroll
            for (int ct = 0; ct < NCT; ++ct) {
                const int jn = jn0 + ct * 16 + s;
#pragma unroll
                for (int r = 0; r < 4; ++r) {
                    const int row = bm + w * 32 + mt * 16 + quad * 4 + r;
                    outp[(size_t)row * 512 + jn] =
                        acc[mt][ct][r] + bias[jn] + bf2f(qkws_ro[(size_t)row * 1024 + jn]);
                }
            }
    } else {
        float rsum[2][NCT / 4][4];
        if constexpr (MODE == MQK) {
#pragma unroll
            for (int mt = 0; mt < 2; ++mt)
#pragma unroll
                for (int hg = 0; hg < NCT / 4; ++hg)
#pragma unroll
                    for (int r = 0; r < 4; ++r) rsum[mt][hg][r] = 0.f;
        }
        __syncthreads();   // final-buf reads (buf0) done; C overlays buf1
#pragma unroll
        for (int mt = 0; mt < 2; ++mt)
#pragma unroll
            for (int ct = 0; ct < NCT; ++ct) {
                const int jn = jn0 + ct * 16 + s;
                const float bj = bias[jn];
#pragma unroll
                for (int r = 0; r < 4; ++r) {
                    const int rowl = w * 32 + mt * 16 + quad * 4 + r;
                    float v = acc[mt][ct][r] + bj;
                    if constexpr (MODE == MVU) {
                        const int row = bm + rowl;
                        v *= kg[(((row >> 10) * 8 + (jn >> 6)) << 10) | (row & 1023)];
                    }
                    if constexpr (MODE == MQK) rsum[mt][ct >> 2][r] += v;
                    Cb[rowl * CST + ct * 16 + s] = f2bf(v);
                }
            }
        if constexpr (MODE == MQK) {
            // fused qs/ks: per-row sum over each 64-col head group
#pragma unroll
            for (int mt = 0; mt < 2; ++mt)
#pragma unroll
                for (int hg = 0; hg < NCT / 4; ++hg)
#pragma unroll
                    for (int r = 0; r < 4; ++r) {
                        float S = rsum[mt][hg][r];
                        S += __shfl_xor(S, 1);
                        S += __shfl_xor(S, 2);
                        S += __shfl_xor(S, 4);
                        S += __shfl_xor(S, 8);
                        if (s == 0) {
                            const int row = bm + w * 32 + mt * 16 + quad * 4 + r;
                            const int jj = jn0 + hg * 64;
                            float* dst = (jj < 512) ? qsout : ksout;
                            dst[((((row >> 10) << 3) | ((jj >> 6) & 7)) << 10) | (row & 1023)] = S;
                        }
                    }
        }
        __syncthreads();
        const int row = t >> 1, ch = (t & 1) * (NCT * 8);
        u16* dp = qkws + (size_t)(bm + row) * 1024 + (MODE == MVU ? 512 : 0) + jn0 + ch;
#pragma unroll
        for (int i = 0; i < NCT; ++i)
            *(uint4*)(dp + i * 8) = *(const uint4*)&Cb[row * CST + ch + i * 8];
    }
}

// ---------------------------------------------------------------------------
// Softmax stage body. Unit u in [0,1024): n0 = (u&15)*64, bh = u>>4.
// Wave w covers m in [w*256, w*256+256). One fma + one v_exp per element.
//   STG=1: rowscale absent, wv=qs     STG=2: rowscale=qg, wv=qg*ks
// zr/wr (2KB) alias the caller's LDS buffer.
// ---------------------------------------------------------------------------
template <int STG>
__device__ __forceinline__ void stage_body(
    u16* smraw, int u,
    const u16* __restrict__ qkws, int qcol0,
    const u16* __restrict__ wmb, const float* __restrict__ biasv,
    const float* __restrict__ rowscale,
    const float* __restrict__ wv1, const float* __restrict__ wv2,
    float* __restrict__ outg)
{
    float* zr = (float*)smraw;        // [4][64]
    float* wr = zr + 256;             // [4][64]
    const int t = threadIdx.x;
    const int w = t >> 6, lane = t & 63, s = lane & 15, quad = lane >> 4;
    const int n0 = (u & 15) * 64;
    const int bh = u >> 4, b = bh >> 3, h = bh & 7;

    short8 qa[4][2];
#pragma unroll
    for (int nt = 0; nt < 4; ++nt)
#pragma unroll
        for (int kk = 0; kk < 2; ++kk)
            qa[nt][kk] = *(const short8*)&qkws[
                (size_t)((b << 10) + n0 + nt * 16 + s) * 1024 + qcol0 + (h << 6) + kk * 32 + quad * 8];

    float rsS[4][4];
#pragma unroll
    for (int nt = 0; nt < 4; ++nt)
#pragma unroll
        for (int r = 0; r < 4; ++r) {
            if constexpr (STG == 2)
                rsS[nt][r] = rowscale[(bh << 10) + n0 + nt * 16 + quad * 4 + r] * SCL2;
            else
                rsS[nt][r] = SCL2;
        }

    float z[4][4] = {}, wa[4][4] = {};

    for (int mi = 0; mi < 16; ++mi) {
        const int mt = w * 256 + mi * 16;
        const u16* bp = wmb + (size_t)(mt + s) * 64 + quad * 8;
        short8 bf0 = *(const short8*)bp;
        short8 bf1 = *(const short8*)(bp + 32);
        const float bm2 = biasv[mt + s] * SCL2;
        float wv = wv1[(bh << 10) + mt + s];
        if constexpr (STG == 2) wv *= wv2[(bh << 10) + mt + s];
#pragma unroll
        for (int nt = 0; nt < 4; ++nt) {
            f32x4 a = (f32x4){0.f, 0.f, 0.f, 0.f};
            a = MFMA16(qa[nt][0], bf0, a);
            a = MFMA16(qa[nt][1], bf1, a);
#pragma unroll
            for (int r = 0; r < 4; ++r) {
                const float e = __builtin_amdgcn_exp2f(rsS[nt][r] * a[r] + bm2);
                z[nt][r] += e;
                wa[nt][r] += e * wv;
            }
        }
    }

    // reduce over the 16 m-lanes of each quad, then across waves via LDS
#pragma unroll
    for (int nt = 0; nt < 4; ++nt)
#pragma unroll
        for (int r = 0; r < 4; ++r) {
            float Z = z[nt][r], W = wa[nt][r];
            for (int off = 1; off < 16; off <<= 1) {
                Z += __shfl_xor(Z, off);
                W += __shfl_xor(W, off);
            }
            if (s == 0) {
                zr[w * 64 + nt * 16 + quad * 4 + r] = Z;
                wr[w * 64 + nt * 16 + quad * 4 + r] = W;
            }
        }
    __syncthreads();
    if (t < 64) {
        float Z = zr[t] + zr[64 + t] + zr[128 + t] + zr[192 + t];
        float W = wr[t] + wr[64 + t] + wr[128 + t] + wr[192 + t];
        outg[(bh << 10) + n0 + t] = W / Z;
    }
}

// ---------------------------------------------------------------------------
// Mega cooperative kernel: QK -> s1 -> s2 -> VU -> OUT with grid syncs.
// 512 blocks x 256 thr; LDS 67.6 KB -> exactly 2 blocks/CU co-resident.
// ---------------------------------------------------------------------------
__global__ __launch_bounds__(256, 2) void mega_kernel(
    const u16* xb, const u16* wqkvb, const u16* woutb,
    const u16* wqb, const u16* wkb,
    const float* b_qkv, const float* bq, const float* bk, const float* b_out,
    float* qs, float* ks, float* qg, float* kg, u16* qkws, float* out)
{
    __shared__ u16 sm[33792];   // QK worst case: 2*HALF(8)=32768, HALF+CELEM=33792
    cg::grid_group grid = cg::this_grid();

    // QK: qk = x @ w_qkv[0:1024]^T + b_qkv  (128x128 tiles) + fused qs/ks
    gemm_body<MQK, 8>(sm, (int)blockIdx.x, xb, 512, 0, wqkvb, b_qkv,
                      nullptr, nullptr, qkws, nullptr, qs, ks);
    grid.sync();
    // stage 1 -> qg  (1024 units, 2 per block)
#pragma unroll
    for (int u = blockIdx.x; u < 1024; u += 512) {
        stage_body<1>(sm, u, qkws, 0, wqb, bq, nullptr, qs, nullptr, qg);
        __syncthreads();
    }
    grid.sync();
    // stage 2 -> kg
#pragma unroll
    for (int u = blockIdx.x; u < 1024; u += 512) {
        stage_body<2>(sm, u, qkws, 512, wkb, bk, qg, qg, ks, kg);
        __syncthreads();
    }
    grid.sync();
    // VU: U = (x @ w_qkv[1024:]^T + bv) * kg  (into k-half of qkws)
    gemm_body<MVU, 4>(sm, (int)blockIdx.x, xb, 512, 0,
                      wqkvb + (size_t)1024 * 512, b_qkv + 1024, kg,
                      nullptr, qkws, nullptr, nullptr, nullptr);
    grid.sync();
    // OUT: out = U @ w_out^T + b_out + qo
    gemm_body<MOUT, 4>(sm, (int)blockIdx.x, qkws, 1024, 512, woutb, b_out,
                       nullptr, qkws, nullptr, out, nullptr, nullptr);
}

// ---------------------------------------------------------------------------
// Fallback standalone kernels (used only if cooperative launch fails)
// ---------------------------------------------------------------------------
template <int MODE, int NCT>
__global__ __launch_bounds__(256) void gemm_k(
    const u16* Ab, int lda, int acol, const u16* Wb, const float* bias,
    const float* kg, const u16* qkws_ro, u16* qkws, float* outp,
    float* qsout, float* ksout)
{
    constexpr int SMSZ = (NCT == 8) ? 33792 : 24576;
    __shared__ u16 sm[SMSZ];
    gemm_body<MODE, NCT>(sm, (int)(blockIdx.y * gridDim.x + blockIdx.x),
                         Ab, lda, acol, Wb, bias, kg, qkws_ro, qkws, outp, qsout, ksout);
}

template <int STG>
__global__ __launch_bounds__(256) void stage_soft_w(
    const u16* qkws, int qcol0, const u16* wmb, const float* biasv,
    const float* rowscale, const float* wv1, const float* wv2, float* outg)
{
    __shared__ float zw[512];
    stage_body<STG>((u16*)zw, (int)(blockIdx.y * 16 + blockIdx.x),
                    qkws, qcol0, wmb, biasv, rowscale, wv1, wv2, outg);
}

// ---------------------------------------------------------------------------
extern "C" void kernel_launch(void* const* d_in, const int* in_sizes, int n_in,
                              void* d_out, int out_size, void* d_ws, size_t ws_size,
                              hipStream_t stream)
{
    const float* x     = (const float*)d_in[0];
    const float* w_qkv = (const float*)d_in[1];
    const float* b_qkv = (const float*)d_in[2];
    const float* wq    = (const float*)d_in[3];
    const float* bq    = (const float*)d_in[4];
    const float* wk    = (const float*)d_in[5];
    const float* bk    = (const float*)d_in[6];
    const float* w_out = (const float*)d_in[7];
    const float* b_out = (const float*)d_in[8];
    float* out = (float*)d_out;

    // ws: qs|ks|qg|kg (65536 f32) | bf16: wqkv|wout|wq|wk|x | qk ws bf16
    float* qs = (float*)d_ws;
    float* ks = qs + 65536;
    float* qg = ks + 65536;
    float* kg = qg + 65536;
    u16* wsb   = (u16*)(kg + 65536);
    u16* wqkvb = wsb;
    u16* woutb = wqkvb + 786432;
    u16* wqb   = woutb + 262144;
    u16* wkb   = wqb + 65536;
    u16* xb    = wkb + 65536;
    u16* qkws  = xb + 4194304;

    // 5,373,952 f32 -> bf16 (weights + x), 4 elems/thread
    conv_kernel<<<5248, 256, 0, stream>>>(w_qkv, w_out, wq, wk, x, wsb);

    const u16* xb_c = xb; const u16* wqkvb_c = wqkvb; const u16* woutb_c = woutb;
    const u16* wqb_c = wqb; const u16* wkb_c = wkb;
    void* args[] = {
        (void*)&xb_c, (void*)&wqkvb_c, (void*)&woutb_c, (void*)&wqb_c, (void*)&wkb_c,
        (void*)&b_qkv, (void*)&bq, (void*)&bk, (void*)&b_out,
        (void*)&qs, (void*)&ks, (void*)&qg, (void*)&kg, (void*)&qkws, (void*)&out };
    hipError_t e = hipLaunchCooperativeKernel(
        (const void*)mega_kernel, dim3(512), dim3(256), args, 0u, stream);
    if (e != hipSuccess) {
        // fallback: separate launches (round-9 structure)
        gemm_k<MQK, 8><<<dim3(64, 8), 256, 0, stream>>>(
            xb, 512, 0, wqkvb, b_qkv, nullptr, nullptr, qkws, nullptr, qs, ks);
        stage_soft_w<1><<<dim3(16, 64), 256, 0, stream>>>(
            qkws, 0, wqb, bq, nullptr, qs, nullptr, qg);
        stage_soft_w<2><<<dim3(16, 64), 256, 0, stream>>>(
            qkws, 512, wkb, bk, qg, qg, ks, kg);
        gemm_k<MVU, 4><<<dim3(64, 8), 256, 0, stream>>>(
            xb, 512, 0, wqkvb + (size_t)1024 * 512, b_qkv + 1024, kg, nullptr, qkws,
            nullptr, nullptr, nullptr);
        gemm_k<MOUT, 4><<<dim3(64, 8), 256, 0, stream>>>(
            qkws, 1024, 512, woutb, b_out, nullptr, qkws, nullptr, out, nullptr, nullptr);
    }
}

// Round 5
// 196.292 us; speedup vs baseline: 2.2023x; 2.2023x over previous
//
#include <hip/hip_runtime.h>

// Fastformer additive attention, MI355X (round 11):
//   - REVERT cooperative mega-kernel (grid.sync ~60us each on 8-XCD: measured
//     336us @ 4% MfmaUtil). Back to round-9 6-kernel structure (183.1us).
//   - gemm_k: T4 counted-vmcnt K-loop. s_waitcnt vmcnt(LOADS)+s_barrier keeps
//     the next tile's 8 gload_lds in flight across the barrier (round 9
//     drained vmcnt(0) every step). Second raw barrier guards WAR.
//   - stage_soft: 1-deep software pipeline of the per-mi weight-fragment /
//     bias / wv loads (L2 latency was serialized into the chain at only
//     4 waves/SIMD).
// Budget (measured r10): ~91us fills (fixed) + ~92us kernels; this attacks
// the kernel term.

#define SCL2 0.1803368801f   /* 0.125 * log2(e) */
typedef unsigned short u16;
typedef __attribute__((ext_vector_type(8))) short short8;   // 8 bf16 = 4 VGPR
typedef __attribute__((ext_vector_type(4))) float f32x4;

#define MFMA16(a, b, c) __builtin_amdgcn_mfma_f32_16x16x32_bf16((a), (b), (c), 0, 0, 0)

__device__ __forceinline__ float bf2f(u16 u) {
    union { unsigned int i; float f; } v; v.i = ((unsigned int)u) << 16; return v.f;
}
__device__ __forceinline__ u16 f2bf(float f) {
    union { float f; unsigned int i; } v; v.f = f;
    unsigned int x = v.i;
    return (u16)((x + 0x7FFFu + ((x >> 16) & 1u)) >> 16);
}

// async global->LDS, 16B per lane; LDS dest = wave-uniform base + lane*16
__device__ __forceinline__ void gload16(const u16* g, u16* l) {
    __builtin_amdgcn_global_load_lds(
        (__attribute__((address_space(1))) void*)(void*)g,
        (__attribute__((address_space(3))) void*)l, 16, 0, 0);
}

template <int N>
__device__ __forceinline__ void waitcnt_vm() {
    if constexpr (N == 8)      asm volatile("s_waitcnt vmcnt(8)" ::: "memory");
    else if constexpr (N == 6) asm volatile("s_waitcnt vmcnt(6)" ::: "memory");
    else                       asm volatile("s_waitcnt vmcnt(0)" ::: "memory");
}

// ---------------------------------------------------------------------------
// f32 -> bf16: w_qkv | w_out | wq | wk | x   (contiguous ws block)
// ---------------------------------------------------------------------------
__global__ __launch_bounds__(256) void conv_kernel(
    const float* __restrict__ w_qkv, const float* __restrict__ w_out,
    const float* __restrict__ wq, const float* __restrict__ wk,
    const float* __restrict__ x, u16* __restrict__ wsb)
{
    const int idx = (blockIdx.x * 256 + threadIdx.x) * 4;
    const float* src; int off;
    if      (idx < 786432)  { src = w_qkv; off = idx; }
    else if (idx < 1048576) { src = w_out; off = idx - 786432; }
    else if (idx < 1114112) { src = wq;    off = idx - 1048576; }
    else if (idx < 1179648) { src = wk;    off = idx - 1114112; }
    else                    { src = x;     off = idx - 1179648; }
    float4 v = *(const float4*)(src + off);
    ushort4 o; o.x = f2bf(v.x); o.y = f2bf(v.y); o.z = f2bf(v.z); o.w = f2bf(v.w);
    *(ushort4*)(wsb + idx) = o;
}

// ---------------------------------------------------------------------------
// MFMA GEMM: tile 128M x (NCT*16)N, BK=64, K=512, 256 thr (4 waves).
// Double-buffered gload_lds staging (linear LDS dest, source chunk swizzled
// with (lane&7)^(lane>>3)); fragment reads XOR chunk idx with (row&7).
// K-loop (T4): stage(next) -> s_waitcnt vmcnt(LOADS) -> s_barrier ->
// compute(cur) -> s_barrier. Next tile's loads stay in flight across both
// barriers; only the epilogue drains vmcnt(0).
// Final compute reads buf0; C bounce (padded stride) overlays buf1.
// ---------------------------------------------------------------------------
#define MQK 0
#define MVU 1
#define MOUT 2

template <int MODE, int NCT>
__global__ __launch_bounds__(256) void gemm_k(
    const u16* __restrict__ Ab, int lda, int acol,
    const u16* __restrict__ Wb, const float* __restrict__ bias,
    const float* __restrict__ kg, const u16* __restrict__ qkws_ro,
    u16* __restrict__ qkws, float* __restrict__ outp,
    float* __restrict__ qsout, float* __restrict__ ksout)
{
    constexpr int BN = NCT * 16;            // tile N
    constexpr int CST = BN + 8;             // padded bounce stride (u16)
    constexpr int ASZ = 128 * 64;           // A elems per buffer
    constexpr int BSZ = BN * 64;            // B elems per buffer
    constexpr int HALF = ASZ + BSZ;         // one double-buffer half
    constexpr int CELEM = 128 * CST;
    constexpr int SMSZ = (2 * HALF > HALF + CELEM) ? 2 * HALF : HALF + CELEM;
    constexpr int LOADS = 4 + NCT / 2;      // gload16 per wave per K-step
    __shared__ u16 sm[SMSZ];
    u16* const Cb = sm + HALF;              // C bounce overlays buf1 only

    const int t = threadIdx.x;
    const int w = t >> 6, lane = t & 63, s = lane & 15, quad = lane >> 4;
    const int sx = lane & 7;                // row&7 of every fragment row read

    // T1: bijective XCD swizzle (nwg % 8 == 0)
    const int nwgy = gridDim.y;
    const int nwg = gridDim.x * nwgy;
    const int flat = blockIdx.y * gridDim.x + blockIdx.x;
    const int swz = (flat & 7) * (nwg >> 3) + (flat >> 3);
    const int by = swz % nwgy, bx = swz / nwgy;
    const int bm = bx * 128, jn0 = by * BN;

    const int r8 = lane >> 3;                       // staged row within 8-row group
    const int c8x = ((lane & 7) ^ r8) << 3;         // swizzled source chunk (u16)

    f32x4 acc[2][NCT];
#pragma unroll
    for (int i = 0; i < 2; ++i)
#pragma unroll
        for (int j = 0; j < NCT; ++j) acc[i][j] = (f32x4){0.f, 0.f, 0.f, 0.f};

    // per-wave staging bases: A rows [w*32, w*32+32), B rows [w*NCT*4, ...)
    const u16* ga = Ab + (size_t)(bm + w * 32 + r8) * lda + acol + c8x;
    const u16* gb = Wb + (size_t)(jn0 + w * (NCT * 4) + r8) * 512 + c8x;

    auto stage = [&](int buf, int kt) {
        u16* la = sm + buf * HALF + (w * 32) * 64;
        u16* lb = sm + buf * HALF + ASZ + (w * (NCT * 4)) * 64;
#pragma unroll
        for (int j = 0; j < 4; ++j)
            gload16(ga + (size_t)j * 8 * lda + kt, la + j * 8 * 64);
#pragma unroll
        for (int j = 0; j < NCT / 2; ++j)
            gload16(gb + (size_t)j * 8 * 512 + kt, lb + j * 8 * 64);
    };
    auto compute = [&](int buf) {
        const u16* Ab_ = sm + buf * HALF;
        const u16* Bb_ = Ab_ + ASZ;
#pragma unroll
        for (int kk = 0; kk < 2; ++kk) {
            const int ca = ((kk * 4 + quad) ^ sx) << 3;   // swizzled read chunk
            short8 a0 = *(const short8*)&Ab_[(w * 32 + s) * 64 + ca];
            short8 a1 = *(const short8*)&Ab_[(w * 32 + 16 + s) * 64 + ca];
#pragma unroll
            for (int ct = 0; ct < NCT; ++ct) {
                short8 bf = *(const short8*)&Bb_[(ct * 16 + s) * 64 + ca];
                acc[0][ct] = MFMA16(a0, bf, acc[0][ct]);
                acc[1][ct] = MFMA16(a1, bf, acc[1][ct]);
            }
        }
    };

    // Pipeline: prologue stages tile0 into buf1; computes alternate 1,0,1,...
    // 7 in-loop computes end on buf1, epilogue computes buf0 (tile 7).
    stage(1, 0);
#pragma unroll
    for (int it = 0; it < 7; ++it) {
        const int cur = 1 - (it & 1);
        stage(1 - cur, 64 * (it + 1));            // issue next-tile loads
        waitcnt_vm<LOADS>();                      // own cur-tile loads complete
        __builtin_amdgcn_s_barrier();             // all waves' cur complete
        __builtin_amdgcn_sched_barrier(0);
        compute(cur);
        __builtin_amdgcn_s_barrier();             // cur reads done -> safe WAR
        __builtin_amdgcn_sched_barrier(0);
    }
    waitcnt_vm<0>();                              // drain tile-7 loads
    __builtin_amdgcn_s_barrier();
    __builtin_amdgcn_sched_barrier(0);
    compute(0);

    if constexpr (MODE == MOUT) {
#pragma unroll
        for (int mt = 0; mt < 2; ++mt)
#pragma unroll
            for (int ct = 0; ct < NCT; ++ct) {
                const int jn = jn0 + ct * 16 + s;
#pragma unroll
                for (int r = 0; r < 4; ++r) {
                    const int row = bm + w * 32 + mt * 16 + quad * 4 + r;
                    outp[(size_t)row * 512 + jn] =
                        acc[mt][ct][r] + bias[jn] + bf2f(qkws_ro[(size_t)row * 1024 + jn]);
                }
            }
    } else {
        float rsum[2][NCT / 4][4];
        if constexpr (MODE == MQK) {
#pragma unroll
            for (int mt = 0; mt < 2; ++mt)
#pragma unroll
                for (int hg = 0; hg < NCT / 4; ++hg)
#pragma unroll
                    for (int r = 0; r < 4; ++r) rsum[mt][hg][r] = 0.f;
        }
        __syncthreads();   // final-buf reads (buf0) done; C overlays buf1
#pragma unroll
        for (int mt = 0; mt < 2; ++mt)
#pragma unroll
            for (int ct = 0; ct < NCT; ++ct) {
                const int jn = jn0 + ct * 16 + s;
                const float bj = bias[jn];
#pragma unroll
                for (int r = 0; r < 4; ++r) {
                    const int rowl = w * 32 + mt * 16 + quad * 4 + r;
                    float v = acc[mt][ct][r] + bj;
                    if constexpr (MODE == MVU) {
                        const int row = bm + rowl;
                        v *= kg[(((row >> 10) * 8 + (jn >> 6)) << 10) | (row & 1023)];
                    }
                    if constexpr (MODE == MQK) rsum[mt][ct >> 2][r] += v;
                    Cb[rowl * CST + ct * 16 + s] = f2bf(v);
                }
            }
        if constexpr (MODE == MQK) {
            // fused qs/ks: per-row sum over each 64-col head group
#pragma unroll
            for (int mt = 0; mt < 2; ++mt)
#pragma unroll
                for (int hg = 0; hg < NCT / 4; ++hg)
#pragma unroll
                    for (int r = 0; r < 4; ++r) {
                        float S = rsum[mt][hg][r];
                        S += __shfl_xor(S, 1);
                        S += __shfl_xor(S, 2);
                        S += __shfl_xor(S, 4);
                        S += __shfl_xor(S, 8);
                        if (s == 0) {
                            const int row = bm + w * 32 + mt * 16 + quad * 4 + r;
                            const int jj = jn0 + hg * 64;
                            float* dst = (jj < 512) ? qsout : ksout;
                            dst[((((row >> 10) << 3) | ((jj >> 6) & 7)) << 10) | (row & 1023)] = S;
                        }
                    }
        }
        __syncthreads();
        const int row = t >> 1, ch = (t & 1) * (NCT * 8);
        u16* dp = qkws + (size_t)(bm + row) * 1024 + (MODE == MVU ? 512 : 0) + jn0 + ch;
#pragma unroll
        for (int i = 0; i < NCT; ++i)
            *(uint4*)(dp + i * 8) = *(const uint4*)&Cb[row * CST + ch + i * 8];
    }
}

// ---------------------------------------------------------------------------
// Softmax stage, barrier-free hot loop with 1-deep software pipeline:
// mi+1's weight fragments / bias / wv are loaded while mi computes, hiding
// the ~200cy L2 chain. Block: 64 n-rows x one (b,h); wave w covers
// m in [w*256, w*256+256). One fma + one v_exp per element.
//   STG=1: qcol0=0,   rowscale absent, wv=qs
//   STG=2: qcol0=512, rowscale=qg,     wv=qg*ks
// ---------------------------------------------------------------------------
template <int STG>
__global__ __launch_bounds__(256) void stage_soft(
    const u16* __restrict__ qkws, int qcol0,
    const u16* __restrict__ wmb, const float* __restrict__ biasv,
    const float* __restrict__ rowscale,
    const float* __restrict__ wv1, const float* __restrict__ wv2,
    float* __restrict__ outg)
{
    __shared__ float zr[4][64], wr[4][64];
    const int t = threadIdx.x;
    const int w = t >> 6, lane = t & 63, s = lane & 15, quad = lane >> 4;
    const int n0 = blockIdx.x * 64;
    const int bh = blockIdx.y, b = bh >> 3, h = bh & 7;

    short8 qa[4][2];
#pragma unroll
    for (int nt = 0; nt < 4; ++nt)
#pragma unroll
        for (int kk = 0; kk < 2; ++kk)
            qa[nt][kk] = *(const short8*)&qkws[
                (size_t)((b << 10) + n0 + nt * 16 + s) * 1024 + qcol0 + (h << 6) + kk * 32 + quad * 8];

    float rsS[4][4];
#pragma unroll
    for (int nt = 0; nt < 4; ++nt)
#pragma unroll
        for (int r = 0; r < 4; ++r) {
            if constexpr (STG == 2)
                rsS[nt][r] = rowscale[(bh << 10) + n0 + nt * 16 + quad * 4 + r] * SCL2;
            else
                rsS[nt][r] = SCL2;
        }

    float z[4][4] = {}, wa[4][4] = {};

    const int mbase = w * 256;
    // prologue: preload mi=0
    const u16* bp0 = wmb + (size_t)(mbase + s) * 64 + quad * 8;
    short8 nb0 = *(const short8*)bp0;
    short8 nb1 = *(const short8*)(bp0 + 32);
    float nbm = biasv[mbase + s];
    float nwv = wv1[(bh << 10) + mbase + s];
    if constexpr (STG == 2) nwv *= wv2[(bh << 10) + mbase + s];

    for (int mi = 0; mi < 16; ++mi) {
        const short8 bf0 = nb0, bf1 = nb1;
        const float bm2 = nbm * SCL2;
        const float wv = nwv;
        if (mi < 15) {   // prefetch mi+1 (uniform branch)
            const int mt = mbase + (mi + 1) * 16;
            const u16* bp = wmb + (size_t)(mt + s) * 64 + quad * 8;
            nb0 = *(const short8*)bp;
            nb1 = *(const short8*)(bp + 32);
            nbm = biasv[mt + s];
            nwv = wv1[(bh << 10) + mt + s];
            if constexpr (STG == 2) nwv *= wv2[(bh << 10) + mt + s];
        }
#pragma unroll
        for (int nt = 0; nt < 4; ++nt) {
            f32x4 a = (f32x4){0.f, 0.f, 0.f, 0.f};
            a = MFMA16(qa[nt][0], bf0, a);
            a = MFMA16(qa[nt][1], bf1, a);
#pragma unroll
            for (int r = 0; r < 4; ++r) {
                const float e = __builtin_amdgcn_exp2f(rsS[nt][r] * a[r] + bm2);
                z[nt][r] += e;
                wa[nt][r] += e * wv;
            }
        }
    }

    // reduce over the 16 m-lanes of each quad, then across waves via LDS
#pragma unroll
    for (int nt = 0; nt < 4; ++nt)
#pragma unroll
        for (int r = 0; r < 4; ++r) {
            float Z = z[nt][r], W = wa[nt][r];
            for (int off = 1; off < 16; off <<= 1) {
                Z += __shfl_xor(Z, off);
                W += __shfl_xor(W, off);
            }
            if (s == 0) {
                zr[w][nt * 16 + quad * 4 + r] = Z;
                wr[w][nt * 16 + quad * 4 + r] = W;
            }
        }
    __syncthreads();
    if (t < 64) {
        float Z = zr[0][t] + zr[1][t] + zr[2][t] + zr[3][t];
        float W = wr[0][t] + wr[1][t] + wr[2][t] + wr[3][t];
        outg[(bh << 10) + n0 + t] = W / Z;
    }
}

// ---------------------------------------------------------------------------
extern "C" void kernel_launch(void* const* d_in, const int* in_sizes, int n_in,
                              void* d_out, int out_size, void* d_ws, size_t ws_size,
                              hipStream_t stream)
{
    const float* x     = (const float*)d_in[0];
    const float* w_qkv = (const float*)d_in[1];
    const float* b_qkv = (const float*)d_in[2];
    const float* wq    = (const float*)d_in[3];
    const float* bq    = (const float*)d_in[4];
    const float* wk    = (const float*)d_in[5];
    const float* bk    = (const float*)d_in[6];
    const float* w_out = (const float*)d_in[7];
    const float* b_out = (const float*)d_in[8];
    float* out = (float*)d_out;

    // ws: qs|ks|qg|kg (65536 f32) | bf16: wqkv|wout|wq|wk|x | qk ws bf16
    float* qs = (float*)d_ws;
    float* ks = qs + 65536;
    float* qg = ks + 65536;
    float* kg = qg + 65536;
    u16* wsb   = (u16*)(kg + 65536);
    u16* wqkvb = wsb;
    u16* woutb = wqkvb + 786432;
    u16* wqb   = woutb + 262144;
    u16* wkb   = wqb + 65536;
    u16* xb    = wkb + 65536;
    u16* qkws  = xb + 4194304;

    // 5,373,952 f32 -> bf16 (weights + x), 4 elems/thread
    conv_kernel<<<5248, 256, 0, stream>>>(w_qkv, w_out, wq, wk, x, wsb);
    // QK: qk = x @ w_qkv[0:1024]^T + b_qkv  (128x128 tile) + fused qs/ks
    gemm_k<MQK, 8><<<dim3(64, 8), 256, 0, stream>>>(
        xb, 512, 0, wqkvb, b_qkv, nullptr, nullptr, qkws, nullptr, qs, ks);
    // stage 1 -> qg
    stage_soft<1><<<dim3(16, 64), 256, 0, stream>>>(
        qkws, 0, wqb, bq, nullptr, qs, nullptr, qg);
    // stage 2 -> kg
    stage_soft<2><<<dim3(16, 64), 256, 0, stream>>>(
        qkws, 512, wkb, bk, qg, qg, ks, kg);
    // VU: U = (x @ w_qkv[1024:]^T + bv) * kg  (into k-half of qk ws)
    gemm_k<MVU, 4><<<dim3(64, 8), 256, 0, stream>>>(
        xb, 512, 0, wqkvb + (size_t)1024 * 512, b_qkv + 1024, kg, nullptr, qkws,
        nullptr, nullptr, nullptr);
    // OUT: out = U @ w_out^T + b_out + qo
    gemm_k<MOUT, 4><<<dim3(64, 8), 256, 0, stream>>>(
        qkws, 1024, 512, woutb, b_out, nullptr, qkws, nullptr, out, nullptr, nullptr);
}